// Round 10
// baseline (144.539 us; speedup 1.0000x reference)
//
#include <hip/hip_runtime.h>
#include <hip/hip_bf16.h>

#define B_ 4
#define N_ 4096
#define D_ 128
#define KSEG 4
#define QSEG 8

typedef __bf16 bf16x8 __attribute__((ext_vector_type(8)));
typedef float f32x4 __attribute__((ext_vector_type(4)));

// alpha = log2(e) / sqrt(128), folded into Qp at conversion time
#define ALPHA 0.12752361680972262f

// ws layout (all fragment-linear packed, 16 B per (tile,frag,lane) chunk):
//   Qp : bf16 [B][256 qstep][4 f][64 lane][8]   @ 0      (4 MiB, alpha-scaled)
//   Kp : bf16 [B][128 kb][8 slot=f*2+ab][64][8] @ 4 MiB  (permuted-key frag order)
//   Vp : bf16 [B][128 kb][8 ds][64][8]          @ 8 MiB  (UNSCALED; 1/l applied to P in attn)
//   l    : f32 [B][N]                           @ 12 MiB (64 KiB)
//   part : f32 [KSEG][B][N][D]                  @ 13 MiB (32 MiB, KSEG=4)
#define OFF_KP   (4u << 20)
#define OFF_VP   (8u << 20)
#define OFF_L    (12u << 20)
#define OFF_PART (13u << 20)

// direct global->LDS DMA, 16 B per lane; LDS dest is wave-uniform base + lane*16
__device__ __forceinline__ void gload_lds16(const void* g, void* s) {
    __builtin_amdgcn_global_load_lds(
        (const __attribute__((address_space(1))) void*)g,
        (__attribute__((address_space(3))) void*)s, 16, 0, 0);
}

// ---------------------------------------------------------------------------
// Kernel A: pack Q*alpha, K (permuted key order), V-transpose (unscaled) into
// fragment-linear layouts. Blocks 2560..2575 zero l. (= R7 cvt: V no longer
// needs l, so it packs up front and the post-stats cvtv pass is eliminated.)
// ---------------------------------------------------------------------------
__global__ __launch_bounds__(256) void cvt_kernel(
    const float* __restrict__ q, const float* __restrict__ k,
    const float* __restrict__ v,
    __bf16* __restrict__ qp, __bf16* __restrict__ kp, __bf16* __restrict__ vp,
    float* __restrict__ l)
{
    __shared__ float vl[32 * 129];   // 16.5 KiB (V section only)

    int bid = blockIdx.x;
    int tid = threadIdx.x;
    if (bid < 2048) {
        int g = (bid & 1023) * 256 + tid;   // 0..262143 within section
        int lane = g & 63;
        int l15 = lane & 15, quad = lane >> 4;
        if (bid < 1024) {
            int f = (g >> 6) & 3;
            int qstep = (g >> 8) & 255;
            int b = g >> 16;
            const float* src = q + ((size_t)(b * N_ + qstep * 16 + l15) * D_ + (f * 4 + quad) * 8);
            float4 x0 = *(const float4*)src;
            float4 x1 = *(const float4*)(src + 4);
            bf16x8 y;
            y[0] = (__bf16)(x0.x * ALPHA); y[1] = (__bf16)(x0.y * ALPHA);
            y[2] = (__bf16)(x0.z * ALPHA); y[3] = (__bf16)(x0.w * ALPHA);
            y[4] = (__bf16)(x1.x * ALPHA); y[5] = (__bf16)(x1.y * ALPHA);
            y[6] = (__bf16)(x1.z * ALPHA); y[7] = (__bf16)(x1.w * ALPHA);
            ((bf16x8*)qp)[g] = y;
        } else {
            int slot = (g >> 6) & 7;
            int kb = (g >> 9) & 127;
            int b = g >> 16;
            int f = slot >> 1, ab = slot & 1;
            int row = kb * 32 + (l15 >> 2) * 8 + (l15 & 3) + ab * 4;
            const float* src = k + ((size_t)(b * N_ + row) * D_ + (f * 4 + quad) * 8);
            float4 x0 = *(const float4*)src;
            float4 x1 = *(const float4*)(src + 4);
            bf16x8 y;
            y[0] = (__bf16)x0.x; y[1] = (__bf16)x0.y; y[2] = (__bf16)x0.z; y[3] = (__bf16)x0.w;
            y[4] = (__bf16)x1.x; y[5] = (__bf16)x1.y; y[6] = (__bf16)x1.z; y[7] = (__bf16)x1.w;
            ((bf16x8*)kp)[g] = y;
        }
    } else if (bid < 2560) {
        int vb = bid - 2048;                // 0..511: one (b, kb) tile
        int b = vb >> 7, kb = vb & 127;
        const float4* src = (const float4*)(v + (size_t)(b * N_ + kb * 32) * D_);
#pragma unroll
        for (int rep = 0; rep < 4; ++rep) {
            int i = rep * 256 + tid;
            int row = i >> 5, c4 = i & 31;
            float4 x = src[row * 32 + c4];
            float* dst = &vl[row * 129 + c4 * 4];
            dst[0] = x.x; dst[1] = x.y; dst[2] = x.z; dst[3] = x.w;
        }
        __syncthreads();
#pragma unroll
        for (int rep = 0; rep < 2; ++rep) {
            int ci = rep * 256 + tid;       // 0..511
            int ds = ci >> 6, ln = ci & 63;
            int quad = ln >> 4, l15 = ln & 15;
            bf16x8 y;
#pragma unroll
            for (int j = 0; j < 8; ++j)
                y[j] = (__bf16)vl[(quad * 8 + j) * 129 + ds * 16 + l15];
            ((bf16x8*)vp)[(((size_t)(b * 128 + kb) * 8) + ds) * 64 + ln] = y;
        }
    } else {
        // zero l: 16 blocks x 256 threads x f32x4 = 16384 floats
        int i = (bid - 2560) * 256 + tid;
        ((f32x4*)l)[i] = (f32x4){0.f, 0.f, 0.f, 0.f};
    }
}

// ---------------------------------------------------------------------------
// Kernel B: column stats, barrier-free streaming (R5 version). UNCHANGED.
// ---------------------------------------------------------------------------
__global__ __launch_bounds__(256, 4) void stats_kernel(
    const __bf16* __restrict__ qp, const __bf16* __restrict__ kp,
    float* __restrict__ l)
{
    int x = blockIdx.x;                   // 1024 blocks
    int xcd = x & 7;
    int i = x >> 3;                       // 0..127
    int b = xcd >> 1;
    int qseg = (xcd & 1) * 4 + (i & 3);   // 0..7
    int kb4 = i >> 2;                     // 0..31

    int w = threadIdx.x >> 6;
    int lane = threadIdx.x & 63;
    int quad = lane >> 4, l15 = lane & 15;
    int kb = kb4 * 4 + w;

    const bf16x8* kc = (const bf16x8*)kp;
    const bf16x8* qc8 = (const bf16x8*)qp;

    bf16x8 af[2][4];
#pragma unroll
    for (int ab = 0; ab < 2; ++ab)
#pragma unroll
        for (int f = 0; f < 4; ++f)
            af[ab][f] = kc[(((size_t)(b * 128 + kb) * 8) + f * 2 + ab) * 64 + lane];

    int qs0 = qseg * 32;                  // this block's 32 q-steps
    const bf16x8* pQ = qc8 + ((size_t)(b * 256 + qs0) * 4) * 64 + lane;

    float ps[8];
#pragma unroll
    for (int s = 0; s < 8; ++s) ps[s] = 0.f;

#pragma unroll 4
    for (int t = 0; t < 32; ++t) {
        bf16x8 qf[4];
#pragma unroll
        for (int f = 0; f < 4; ++f)
            qf[f] = pQ[(size_t)t * 256 + f * 64];
#pragma unroll
        for (int ab = 0; ab < 2; ++ab) {
            f32x4 acc = {0.f, 0.f, 0.f, 0.f};
#pragma unroll
            for (int f = 0; f < 4; ++f)
                acc = __builtin_amdgcn_mfma_f32_16x16x32_bf16(af[ab][f], qf[f], acc, 0, 0, 0);
#pragma unroll
            for (int r = 0; r < 4; ++r)
                ps[ab * 4 + r] += __builtin_amdgcn_exp2f(acc[r]);
        }
    }
#pragma unroll
    for (int m = 1; m <= 8; m <<= 1)
#pragma unroll
        for (int s = 0; s < 8; ++s)
            ps[s] += __shfl_xor(ps[s], m, 64);
    if (l15 == 0) {
        // permuted C rows: key = kb*32 + quad*8 + ab*4 + r
        float* dst = l + (size_t)b * N_ + kb * 32 + quad * 8;
#pragma unroll
        for (int ab = 0; ab < 2; ++ab)
#pragma unroll
            for (int r = 0; r < 4; ++r)
                atomicAdd(dst + ab * 4 + r, ps[ab * 4 + r]);
    }
}

// ---------------------------------------------------------------------------
// Kernel D: attention — R9 core (512-thr 8-wave, s=2, 3-buffer LDS ring, one
// __syncthreads per tile, XCD swizzle, KSEG=4, part epilogue). NEW: 1/l is
// applied to P (pb = exp2(acc) * rcp_l[key]) instead of pre-scaled V. The
// per-block rcp-l table (1024 keys, 4 KiB) is staged into LDS once in the
// prologue; per-tile reads are 16-lane broadcasts (conflict-free).
// ---------------------------------------------------------------------------
__global__ __launch_bounds__(512, 2) void attn_kernel(
    const __bf16* __restrict__ qp, const __bf16* __restrict__ kp,
    const __bf16* __restrict__ vp, const float* __restrict__ l,
    float* __restrict__ part)
{
    __shared__ __bf16 lds[3][16 * 512];   // 3 x 16 KiB ring: chunks 0-7 K, 8-15 V
    __shared__ float rl_lds[1024];        // rcp(l) for this seg's 1024 keys

    // swizzle: the 16 qtile-blocks of one (b,seg) share one XCD (2 groups/XCD)
    int x = blockIdx.x;                   // 256 blocks
    int xcd = x & 7;
    int i = x >> 3;                       // 0..31
    int group = xcd * 2 + (i & 1);        // 0..15 = (b,seg)
    int qtile = i >> 1;                   // 0..15 (256 q each)
    int b = group >> 2;
    int seg = group & 3;

    int w = threadIdx.x >> 6;             // 0..7
    int lane = threadIdx.x & 63;
    int quad = lane >> 4, l15 = lane & 15;

    const bf16x8* qc8 = (const bf16x8*)qp;
    const bf16x8* kc = (const bf16x8*)kp;
    const bf16x8* vc = (const bf16x8*)vp;

    int q0w = qtile * 256 + w * 32;       // this wave's 32 q rows
    int qstep0 = qtile * 16 + w * 2;
    bf16x8 bq[2][4];
#pragma unroll
    for (int s = 0; s < 2; ++s)
#pragma unroll
        for (int f = 0; f < 4; ++f)
            bq[s][f] = qc8[((size_t)(b * 256 + qstep0 + s) * 4 + f) * 64 + lane];

    f32x4 oacc[2][8];
#pragma unroll
    for (int s = 0; s < 2; ++s)
#pragma unroll
        for (int d = 0; d < 8; ++d) oacc[s][d] = (f32x4){0.f, 0.f, 0.f, 0.f};

    int kb0 = seg * 32;                   // 32 kb tiles per segment
    const bf16x8* pK = kc + (((size_t)(b * 128 + kb0) * 8) + w) * 64 + lane;
    const bf16x8* pV = vc + (((size_t)(b * 128 + kb0) * 8) + w) * 64 + lane;

#define QK_COMPUTE(bufk) \
    { \
        bf16x8 akA[4], akB[4]; \
        _Pragma("unroll") \
        for (int f = 0; f < 4; ++f) { \
            akA[f] = *(const bf16x8*)((bufk) + (f * 2 + 0) * 512 + lane * 8); \
            akB[f] = *(const bf16x8*)((bufk) + (f * 2 + 1) * 512 + lane * 8); \
        } \
        _Pragma("unroll") \
        for (int s = 0; s < 2; ++s) { \
            accA[s] = (f32x4){0.f, 0.f, 0.f, 0.f}; \
            accB[s] = (f32x4){0.f, 0.f, 0.f, 0.f}; \
            _Pragma("unroll") \
            for (int f = 0; f < 4; ++f) { \
                accA[s] = __builtin_amdgcn_mfma_f32_16x16x32_bf16(akA[f], bq[s][f], accA[s], 0, 0, 0); \
                accB[s] = __builtin_amdgcn_mfma_f32_16x16x32_bf16(akB[f], bq[s][f], accB[s], 0, 0, 0); \
            } \
        } \
    }

#define PV_COMPUTE(bufv) \
    { \
        _Pragma("unroll") \
        for (int ds = 0; ds < 8; ++ds) { \
            bf16x8 vf = *(const bf16x8*)((bufv) + (8 + ds) * 512 + lane * 8); \
            _Pragma("unroll") \
            for (int s = 0; s < 2; ++s) \
                oacc[s][ds] = __builtin_amdgcn_mfma_f32_16x16x32_bf16(vf, pb[s], oacc[s][ds], 0, 0, 0); \
        } \
    }

// key of pb[s][ab*4+r] = kb*32 + quad*8 + ab*4 + r -> rl0 covers ab=0, rl1 ab=1
#define EXP_TO_PB(tt) \
    { \
        f32x4 rl0 = *(const f32x4*)&rl_lds[(tt) * 32 + quad * 8]; \
        f32x4 rl1 = *(const f32x4*)&rl_lds[(tt) * 32 + quad * 8 + 4]; \
        _Pragma("unroll") \
        for (int s = 0; s < 2; ++s) { \
            pb[s][0] = (__bf16)(__builtin_amdgcn_exp2f(accA[s][0]) * rl0[0]); \
            pb[s][1] = (__bf16)(__builtin_amdgcn_exp2f(accA[s][1]) * rl0[1]); \
            pb[s][2] = (__bf16)(__builtin_amdgcn_exp2f(accA[s][2]) * rl0[2]); \
            pb[s][3] = (__bf16)(__builtin_amdgcn_exp2f(accA[s][3]) * rl0[3]); \
            pb[s][4] = (__bf16)(__builtin_amdgcn_exp2f(accB[s][0]) * rl1[0]); \
            pb[s][5] = (__bf16)(__builtin_amdgcn_exp2f(accB[s][1]) * rl1[1]); \
            pb[s][6] = (__bf16)(__builtin_amdgcn_exp2f(accB[s][2]) * rl1[2]); \
            pb[s][7] = (__bf16)(__builtin_amdgcn_exp2f(accB[s][3]) * rl1[3]); \
        } \
    }

    bf16x8 pb[2];                         // scaled P of tile t-1 (carried)
    f32x4 accA[2], accB[2];

    // prologue: stage tile 0 DMA; stage rcp(l) table (1024 keys) into LDS
    gload_lds16(pK, &lds[0][w * 512]);
    gload_lds16(pV, &lds[0][(8 + w) * 512]);
    {
        const float* lsrc = l + (size_t)b * N_ + kb0 * 32;
#pragma unroll
        for (int ii = 0; ii < 2; ++ii) {
            int idx = ii * 512 + threadIdx.x;
            rl_lds[idx] = __builtin_amdgcn_rcpf(lsrc[idx]);
        }
    }
    __syncthreads();

    // peel t=0: DMA(1); QK(0); exp*rl -> pb; no PV yet
    {
        gload_lds16(pK + 512, &lds[1][w * 512]);
        gload_lds16(pV + 512, &lds[1][(8 + w) * 512]);
        const __bf16* bufk = &lds[0][0];
        QK_COMPUTE(bufk)
        EXP_TO_PB(0)
        __syncthreads();                  // DMA(1) landed; lds[0] V still live
    }

    int cur = 1;                          // = t % 3
    for (int t = 1; t < 32; ++t) {
        int prv = (cur == 0) ? 2 : cur - 1;   // (t-1) % 3: V of tile t-1
        int nxt = (cur == 2) ? 0 : cur + 1;   // (t+1) % 3: DMA dest
        if (t + 1 < 32) {
            gload_lds16(pK + (size_t)(t + 1) * 512, &lds[nxt][w * 512]);
            gload_lds16(pV + (size_t)(t + 1) * 512, &lds[nxt][(8 + w) * 512]);
        }
        const __bf16* bufk = &lds[cur][0];
        const __bf16* bufv = &lds[prv][0];
        QK_COMPUTE(bufk)                  // MFMA on tile t
        PV_COMPUTE(bufv)                  // MFMA on tile t-1 (independent)
        EXP_TO_PB(t)                      // VALU on tile t (indep of PV)
        __syncthreads();                  // DMA(t+1) landed; reads done
        cur = nxt;
    }
    {   // epilogue: PV(31); tile 31 is in lds[31 % 3] = lds[1]
        const __bf16* bufv = &lds[1][0];
        PV_COMPUTE(bufv)
    }
#undef QK_COMPUTE
#undef PV_COMPUTE
#undef EXP_TO_PB

    float* op = part + ((size_t)seg * B_ * N_ + (size_t)b * N_ + q0w) * D_;
#pragma unroll
    for (int s = 0; s < 2; ++s)
#pragma unroll
        for (int ds = 0; ds < 8; ++ds) {
            float4 o4;
            o4.x = oacc[s][ds][0]; o4.y = oacc[s][ds][1];
            o4.z = oacc[s][ds][2]; o4.w = oacc[s][ds][3];
            *(float4*)(op + (size_t)(s * 16 + l15) * D_ + ds * 16 + quad * 4) = o4;
        }
}

// ---------------------------------------------------------------------------
// Kernel E: out = sum of KSEG partials
// ---------------------------------------------------------------------------
__global__ __launch_bounds__(256) void reduce_kernel(
    const float* __restrict__ part, float* __restrict__ out)
{
    int i = blockIdx.x * 256 + threadIdx.x;
    const f32x4* p = (const f32x4*)part;
    f32x4 s = p[i];
#pragma unroll
    for (int sgi = 1; sgi < KSEG; ++sgi) {
        f32x4 t = p[(size_t)sgi * (B_ * N_ * D_ / 4) + i];
        s[0] += t[0]; s[1] += t[1]; s[2] += t[2]; s[3] += t[3];
    }
    ((f32x4*)out)[i] = s;
}

extern "C" void kernel_launch(void* const* d_in, const int* in_sizes, int n_in,
                              void* d_out, int out_size, void* d_ws, size_t ws_size,
                              hipStream_t stream) {
    const float* q = (const float*)d_in[0];
    const float* k = (const float*)d_in[1];
    const float* v = (const float*)d_in[2];
    float* out = (float*)d_out;
    char* ws = (char*)d_ws;
    __bf16* qp = (__bf16*)(ws);
    __bf16* kp = (__bf16*)(ws + OFF_KP);
    __bf16* vp = (__bf16*)(ws + OFF_VP);
    float* l    = (float*)(ws + OFF_L);
    float* part = (float*)(ws + OFF_PART);

    hipLaunchKernelGGL(cvt_kernel, dim3(2576), dim3(256), 0, stream, q, k, v, qp, kp, vp, l);
    hipLaunchKernelGGL(stats_kernel, dim3(1024), dim3(256), 0, stream, qp, kp, l);
    hipLaunchKernelGGL(attn_kernel, dim3(B_ * 16 * KSEG), dim3(512), 0, stream, qp, kp, vp, l, part);
    hipLaunchKernelGGL(reduce_kernel, dim3(B_ * N_ * D_ / 4 / 256), dim3(256), 0, stream, part, out);
}

// Round 11
// 139.284 us; speedup vs baseline: 1.0377x; 1.0377x over previous
//
#include <hip/hip_runtime.h>
#include <hip/hip_bf16.h>

#define B_ 4
#define N_ 4096
#define D_ 128
#define KSEG 4
#define QSEG 8

typedef __bf16 bf16x8 __attribute__((ext_vector_type(8)));
typedef float f32x4 __attribute__((ext_vector_type(4)));

// alpha = log2(e) / sqrt(128), folded into Qp at conversion time
#define ALPHA 0.12752361680972262f

// ws layout (all fragment-linear packed, 16 B per (tile,frag,lane) chunk):
//   Qp : bf16 [B][256 qstep][4 f][64 lane][8]   @ 0      (4 MiB, alpha-scaled)
//   Kp : bf16 [B][128 kb][8 slot=f*2+ab][64][8] @ 4 MiB  (permuted-key frag order)
//   Vp : bf16 [B][128 kb][8 ds][64][8]          @ 8 MiB  (1/l folded at pack time)
//   l    : f32 [B][N]                           @ 12 MiB (64 KiB)
//   part : f32 [KSEG][B][N][D]                  @ 13 MiB (32 MiB, KSEG=4)
#define OFF_KP   (4u << 20)
#define OFF_VP   (8u << 20)
#define OFF_L    (12u << 20)
#define OFF_PART (13u << 20)

// direct global->LDS DMA, 16 B per lane; LDS dest is wave-uniform base + lane*16
__device__ __forceinline__ void gload_lds16(const void* g, void* s) {
    __builtin_amdgcn_global_load_lds(
        (const __attribute__((address_space(1))) void*)g,
        (__attribute__((address_space(3))) void*)s, 16, 0, 0);
}

// ---------------------------------------------------------------------------
// Kernel A: pack Q*alpha and K (permuted key order). Blocks 2048..2063 zero l.
// (V handled by cvtv_kernel; keeps the pre-stats critical path short.)
// ---------------------------------------------------------------------------
__global__ __launch_bounds__(256) void cvt_qk_kernel(
    const float* __restrict__ q, const float* __restrict__ k,
    __bf16* __restrict__ qp, __bf16* __restrict__ kp,
    float* __restrict__ l)
{
    int bid = blockIdx.x;
    int tid = threadIdx.x;
    if (bid < 2048) {
        int g = (bid & 1023) * 256 + tid;   // 0..262143 within section
        int lane = g & 63;
        int l15 = lane & 15, quad = lane >> 4;
        if (bid < 1024) {
            int f = (g >> 6) & 3;
            int qstep = (g >> 8) & 255;
            int b = g >> 16;
            const float* src = q + ((size_t)(b * N_ + qstep * 16 + l15) * D_ + (f * 4 + quad) * 8);
            float4 x0 = *(const float4*)src;
            float4 x1 = *(const float4*)(src + 4);
            bf16x8 y;
            y[0] = (__bf16)(x0.x * ALPHA); y[1] = (__bf16)(x0.y * ALPHA);
            y[2] = (__bf16)(x0.z * ALPHA); y[3] = (__bf16)(x0.w * ALPHA);
            y[4] = (__bf16)(x1.x * ALPHA); y[5] = (__bf16)(x1.y * ALPHA);
            y[6] = (__bf16)(x1.z * ALPHA); y[7] = (__bf16)(x1.w * ALPHA);
            ((bf16x8*)qp)[g] = y;
        } else {
            int slot = (g >> 6) & 7;
            int kb = (g >> 9) & 127;
            int b = g >> 16;
            int f = slot >> 1, ab = slot & 1;
            int row = kb * 32 + (l15 >> 2) * 8 + (l15 & 3) + ab * 4;
            const float* src = k + ((size_t)(b * N_ + row) * D_ + (f * 4 + quad) * 8);
            float4 x0 = *(const float4*)src;
            float4 x1 = *(const float4*)(src + 4);
            bf16x8 y;
            y[0] = (__bf16)x0.x; y[1] = (__bf16)x0.y; y[2] = (__bf16)x0.z; y[3] = (__bf16)x0.w;
            y[4] = (__bf16)x1.x; y[5] = (__bf16)x1.y; y[6] = (__bf16)x1.z; y[7] = (__bf16)x1.w;
            ((bf16x8*)kp)[g] = y;
        }
    } else {
        // zero l: 16 blocks x 256 threads x f32x4 = 16384 floats
        int i = (bid - 2048) * 256 + tid;
        ((f32x4*)l)[i] = (f32x4){0.f, 0.f, 0.f, 0.f};
    }
}

// ---------------------------------------------------------------------------
// Kernel B: column stats, barrier-free streaming (R5 version). UNCHANGED.
// ---------------------------------------------------------------------------
__global__ __launch_bounds__(256, 4) void stats_kernel(
    const __bf16* __restrict__ qp, const __bf16* __restrict__ kp,
    float* __restrict__ l)
{
    int x = blockIdx.x;                   // 1024 blocks
    int xcd = x & 7;
    int i = x >> 3;                       // 0..127
    int b = xcd >> 1;
    int qseg = (xcd & 1) * 4 + (i & 3);   // 0..7
    int kb4 = i >> 2;                     // 0..31

    int w = threadIdx.x >> 6;
    int lane = threadIdx.x & 63;
    int quad = lane >> 4, l15 = lane & 15;
    int kb = kb4 * 4 + w;

    const bf16x8* kc = (const bf16x8*)kp;
    const bf16x8* qc8 = (const bf16x8*)qp;

    bf16x8 af[2][4];
#pragma unroll
    for (int ab = 0; ab < 2; ++ab)
#pragma unroll
        for (int f = 0; f < 4; ++f)
            af[ab][f] = kc[(((size_t)(b * 128 + kb) * 8) + f * 2 + ab) * 64 + lane];

    int qs0 = qseg * 32;                  // this block's 32 q-steps
    const bf16x8* pQ = qc8 + ((size_t)(b * 256 + qs0) * 4) * 64 + lane;

    float ps[8];
#pragma unroll
    for (int s = 0; s < 8; ++s) ps[s] = 0.f;

#pragma unroll 4
    for (int t = 0; t < 32; ++t) {
        bf16x8 qf[4];
#pragma unroll
        for (int f = 0; f < 4; ++f)
            qf[f] = pQ[(size_t)t * 256 + f * 64];
#pragma unroll
        for (int ab = 0; ab < 2; ++ab) {
            f32x4 acc = {0.f, 0.f, 0.f, 0.f};
#pragma unroll
            for (int f = 0; f < 4; ++f)
                acc = __builtin_amdgcn_mfma_f32_16x16x32_bf16(af[ab][f], qf[f], acc, 0, 0, 0);
#pragma unroll
            for (int r = 0; r < 4; ++r)
                ps[ab * 4 + r] += __builtin_amdgcn_exp2f(acc[r]);
        }
    }
#pragma unroll
    for (int m = 1; m <= 8; m <<= 1)
#pragma unroll
        for (int s = 0; s < 8; ++s)
            ps[s] += __shfl_xor(ps[s], m, 64);
    if (l15 == 0) {
        // permuted C rows: key = kb*32 + quad*8 + ab*4 + r
        float* dst = l + (size_t)b * N_ + kb * 32 + quad * 8;
#pragma unroll
        for (int ab = 0; ab < 2; ++ab)
#pragma unroll
            for (int r = 0; r < 4; ++r)
                atomicAdd(dst + ab * 4 + r, ps[ab * 4 + r]);
    }
}

// ---------------------------------------------------------------------------
// Kernel C: V transpose + 1/l scale fused. fp32 scale before the single bf16
// rounding; one pass over V. 512 blocks, one (b, kb) tile each.
// ---------------------------------------------------------------------------
__global__ __launch_bounds__(256) void cvtv_kernel(
    const float* __restrict__ v, const float* __restrict__ l,
    __bf16* __restrict__ vp)
{
    __shared__ float vl[32 * 129];   // 16.5 KiB

    int vb = blockIdx.x;                 // 0..511
    int tid = threadIdx.x;
    int b = vb >> 7, kb = vb & 127;
    const float4* src = (const float4*)(v + (size_t)(b * N_ + kb * 32) * D_);
#pragma unroll
    for (int rep = 0; rep < 4; ++rep) {
        int i = rep * 256 + tid;
        int row = i >> 5, c4 = i & 31;
        float4 x = src[row * 32 + c4];
        float* dst = &vl[row * 129 + c4 * 4];
        dst[0] = x.x; dst[1] = x.y; dst[2] = x.z; dst[3] = x.w;
    }
    __syncthreads();

    int ln = tid & 63;
    int quad = ln >> 4, l15 = ln & 15;
    const float* lp = l + (size_t)b * N_ + kb * 32 + quad * 8;
    float4 a = *(const float4*)lp;
    float4 c = *(const float4*)(lp + 4);
    float rl[8];
    rl[0] = __builtin_amdgcn_rcpf(a.x); rl[1] = __builtin_amdgcn_rcpf(a.y);
    rl[2] = __builtin_amdgcn_rcpf(a.z); rl[3] = __builtin_amdgcn_rcpf(a.w);
    rl[4] = __builtin_amdgcn_rcpf(c.x); rl[5] = __builtin_amdgcn_rcpf(c.y);
    rl[6] = __builtin_amdgcn_rcpf(c.z); rl[7] = __builtin_amdgcn_rcpf(c.w);

#pragma unroll
    for (int rep = 0; rep < 2; ++rep) {
        int ci = rep * 256 + tid;        // 0..511
        int ds = ci >> 6;                // rep0: 0..3, rep1: 4..7
        bf16x8 y;
#pragma unroll
        for (int j = 0; j < 8; ++j)
            y[j] = (__bf16)(vl[(quad * 8 + j) * 129 + ds * 16 + l15] * rl[j]);
        ((bf16x8*)vp)[(((size_t)(b * 128 + kb) * 8) + ds) * 64 + ln] = y;
    }
}

// ---------------------------------------------------------------------------
// Kernel D: attention — best measured form (42.7 µs, MfmaUtil 30, conflicts
// 0). 512-thr 8-wave, s=2, 3-buffer LDS ring, one __syncthreads per tile,
// XCD swizzle, KSEG=4, part epilogue. No fences (R8), no rl-in-loop (R10),
// no phase pinning (R6) — all measured regressions.
// ---------------------------------------------------------------------------
__global__ __launch_bounds__(512, 2) void attn_kernel(
    const __bf16* __restrict__ qp, const __bf16* __restrict__ kp,
    const __bf16* __restrict__ vp, float* __restrict__ part)
{
    __shared__ __bf16 lds[3][16 * 512];   // 3 x 16 KiB ring: chunks 0-7 K, 8-15 V

    // swizzle: the 16 qtile-blocks of one (b,seg) share one XCD (2 groups/XCD)
    int x = blockIdx.x;                   // 256 blocks
    int xcd = x & 7;
    int i = x >> 3;                       // 0..31
    int group = xcd * 2 + (i & 1);        // 0..15 = (b,seg)
    int qtile = i >> 1;                   // 0..15 (256 q each)
    int b = group >> 2;
    int seg = group & 3;

    int w = threadIdx.x >> 6;             // 0..7
    int lane = threadIdx.x & 63;
    int quad = lane >> 4, l15 = lane & 15;

    const bf16x8* qc8 = (const bf16x8*)qp;
    const bf16x8* kc = (const bf16x8*)kp;
    const bf16x8* vc = (const bf16x8*)vp;

    int q0w = qtile * 256 + w * 32;       // this wave's 32 q rows
    int qstep0 = qtile * 16 + w * 2;
    bf16x8 bq[2][4];
#pragma unroll
    for (int s = 0; s < 2; ++s)
#pragma unroll
        for (int f = 0; f < 4; ++f)
            bq[s][f] = qc8[((size_t)(b * 256 + qstep0 + s) * 4 + f) * 64 + lane];

    f32x4 oacc[2][8];
#pragma unroll
    for (int s = 0; s < 2; ++s)
#pragma unroll
        for (int d = 0; d < 8; ++d) oacc[s][d] = (f32x4){0.f, 0.f, 0.f, 0.f};

    int kb0 = seg * 32;                   // 32 kb tiles per segment
    const bf16x8* pK = kc + (((size_t)(b * 128 + kb0) * 8) + w) * 64 + lane;
    const bf16x8* pV = vc + (((size_t)(b * 128 + kb0) * 8) + w) * 64 + lane;

#define QK_COMPUTE(bufk) \
    { \
        bf16x8 akA[4], akB[4]; \
        _Pragma("unroll") \
        for (int f = 0; f < 4; ++f) { \
            akA[f] = *(const bf16x8*)((bufk) + (f * 2 + 0) * 512 + lane * 8); \
            akB[f] = *(const bf16x8*)((bufk) + (f * 2 + 1) * 512 + lane * 8); \
        } \
        _Pragma("unroll") \
        for (int s = 0; s < 2; ++s) { \
            accA[s] = (f32x4){0.f, 0.f, 0.f, 0.f}; \
            accB[s] = (f32x4){0.f, 0.f, 0.f, 0.f}; \
            _Pragma("unroll") \
            for (int f = 0; f < 4; ++f) { \
                accA[s] = __builtin_amdgcn_mfma_f32_16x16x32_bf16(akA[f], bq[s][f], accA[s], 0, 0, 0); \
                accB[s] = __builtin_amdgcn_mfma_f32_16x16x32_bf16(akB[f], bq[s][f], accB[s], 0, 0, 0); \
            } \
        } \
    }

#define PV_COMPUTE(bufv) \
    { \
        _Pragma("unroll") \
        for (int ds = 0; ds < 8; ++ds) { \
            bf16x8 vf = *(const bf16x8*)((bufv) + (8 + ds) * 512 + lane * 8); \
            _Pragma("unroll") \
            for (int s = 0; s < 2; ++s) \
                oacc[s][ds] = __builtin_amdgcn_mfma_f32_16x16x32_bf16(vf, pb[s], oacc[s][ds], 0, 0, 0); \
        } \
    }

#define EXP_TO_PB() \
    { \
        _Pragma("unroll") \
        for (int s = 0; s < 2; ++s) { \
            pb[s][0] = (__bf16)__builtin_amdgcn_exp2f(accA[s][0]); \
            pb[s][1] = (__bf16)__builtin_amdgcn_exp2f(accA[s][1]); \
            pb[s][2] = (__bf16)__builtin_amdgcn_exp2f(accA[s][2]); \
            pb[s][3] = (__bf16)__builtin_amdgcn_exp2f(accA[s][3]); \
            pb[s][4] = (__bf16)__builtin_amdgcn_exp2f(accB[s][0]); \
            pb[s][5] = (__bf16)__builtin_amdgcn_exp2f(accB[s][1]); \
            pb[s][6] = (__bf16)__builtin_amdgcn_exp2f(accB[s][2]); \
            pb[s][7] = (__bf16)__builtin_amdgcn_exp2f(accB[s][3]); \
        } \
    }

    bf16x8 pb[2];                         // exp'd P of tile t-1 (carried)
    f32x4 accA[2], accB[2];

    // prologue: stage tile 0, drain
    gload_lds16(pK, &lds[0][w * 512]);
    gload_lds16(pV, &lds[0][(8 + w) * 512]);
    __syncthreads();

    // peel t=0: DMA(1); QK(0); exp -> pb; no PV yet
    {
        gload_lds16(pK + 512, &lds[1][w * 512]);
        gload_lds16(pV + 512, &lds[1][(8 + w) * 512]);
        const __bf16* bufk = &lds[0][0];
        QK_COMPUTE(bufk)
        EXP_TO_PB()
        __syncthreads();                  // DMA(1) landed; lds[0] V still live
    }

    int cur = 1;                          // = t % 3
    for (int t = 1; t < 32; ++t) {
        int prv = (cur == 0) ? 2 : cur - 1;   // (t-1) % 3: V of tile t-1
        int nxt = (cur == 2) ? 0 : cur + 1;   // (t+1) % 3: DMA dest
        if (t + 1 < 32) {
            gload_lds16(pK + (size_t)(t + 1) * 512, &lds[nxt][w * 512]);
            gload_lds16(pV + (size_t)(t + 1) * 512, &lds[nxt][(8 + w) * 512]);
        }
        const __bf16* bufk = &lds[cur][0];
        const __bf16* bufv = &lds[prv][0];
        QK_COMPUTE(bufk)                  // MFMA on tile t
        PV_COMPUTE(bufv)                  // MFMA on tile t-1 (independent)
        EXP_TO_PB()                       // VALU on tile t (indep of PV)
        __syncthreads();                  // DMA(t+1) landed; reads done
        cur = nxt;
    }
    {   // epilogue: PV(31); tile 31 is in lds[31 % 3] = lds[1]
        const __bf16* bufv = &lds[1][0];
        PV_COMPUTE(bufv)
    }
#undef QK_COMPUTE
#undef PV_COMPUTE
#undef EXP_TO_PB

    float* op = part + ((size_t)seg * B_ * N_ + (size_t)b * N_ + q0w) * D_;
#pragma unroll
    for (int s = 0; s < 2; ++s)
#pragma unroll
        for (int ds = 0; ds < 8; ++ds) {
            float4 o4;
            o4.x = oacc[s][ds][0]; o4.y = oacc[s][ds][1];
            o4.z = oacc[s][ds][2]; o4.w = oacc[s][ds][3];
            *(float4*)(op + (size_t)(s * 16 + l15) * D_ + ds * 16 + quad * 4) = o4;
        }
}

// ---------------------------------------------------------------------------
// Kernel E: out = sum of KSEG partials
// ---------------------------------------------------------------------------
__global__ __launch_bounds__(256) void reduce_kernel(
    const float* __restrict__ part, float* __restrict__ out)
{
    int i = blockIdx.x * 256 + threadIdx.x;
    const f32x4* p = (const f32x4*)part;
    f32x4 s = p[i];
#pragma unroll
    for (int sgi = 1; sgi < KSEG; ++sgi) {
        f32x4 t = p[(size_t)sgi * (B_ * N_ * D_ / 4) + i];
        s[0] += t[0]; s[1] += t[1]; s[2] += t[2]; s[3] += t[3];
    }
    ((f32x4*)out)[i] = s;
}

extern "C" void kernel_launch(void* const* d_in, const int* in_sizes, int n_in,
                              void* d_out, int out_size, void* d_ws, size_t ws_size,
                              hipStream_t stream) {
    const float* q = (const float*)d_in[0];
    const float* k = (const float*)d_in[1];
    const float* v = (const float*)d_in[2];
    float* out = (float*)d_out;
    char* ws = (char*)d_ws;
    __bf16* qp = (__bf16*)(ws);
    __bf16* kp = (__bf16*)(ws + OFF_KP);
    __bf16* vp = (__bf16*)(ws + OFF_VP);
    float* l    = (float*)(ws + OFF_L);
    float* part = (float*)(ws + OFF_PART);

    hipLaunchKernelGGL(cvt_qk_kernel, dim3(2064), dim3(256), 0, stream, q, k, qp, kp, l);
    hipLaunchKernelGGL(stats_kernel, dim3(1024), dim3(256), 0, stream, qp, kp, l);
    hipLaunchKernelGGL(cvtv_kernel, dim3(512), dim3(256), 0, stream, v, l, vp);
    hipLaunchKernelGGL(attn_kernel, dim3(B_ * 16 * KSEG), dim3(512), 0, stream, qp, kp, vp, part);
    hipLaunchKernelGGL(reduce_kernel, dim3(B_ * N_ * D_ / 4 / 256), dim3(256), 0, stream, part, out);
}